// Round 8
// baseline (403.781 us; speedup 1.0000x reference)
//
#include <hip/hip_runtime.h>
#include <hip/hip_bf16.h>

typedef __attribute__((ext_vector_type(4))) float f32x4;
typedef __attribute__((ext_vector_type(8))) short bf16x8;
typedef unsigned short u16;

#define SEQ 2048
#define HID 1024
#define NROWS 16384

// ---------- helpers ----------
__device__ __forceinline__ float b2f(u16 u) {
    union { float f; unsigned i; } x; x.i = ((unsigned)u) << 16; return x.f;
}
__device__ __forceinline__ u16 f2b(float f) {
    unsigned x = __float_as_uint(f);
    return (u16)((x + 0x7fffu + ((x >> 16) & 1u)) >> 16);
}
__device__ __forceinline__ void gload16(const u16* g, u16* l) {
    __builtin_amdgcn_global_load_lds(
        (const __attribute__((address_space(1))) void*)g,
        (__attribute__((address_space(3))) void*)l,
        16, 0, 0);
}

// ---------- fp32 -> bf16 convert ----------
__global__ __launch_bounds__(256)
void cvt_kernel(const float* __restrict__ src, u16* __restrict__ dst, int n) {
    int base = (blockIdx.x * 256 + threadIdx.x) * 4;
    if (base < n) {
        float4 v = *(const float4*)&src[base];
        ushort4 o;
        o.x = f2b(v.x); o.y = f2b(v.y); o.z = f2b(v.z); o.w = f2b(v.w);
        *(ushort4*)&dst[base] = o;
    }
}

// ---------- GEMM: C = A @ B^T (+bias)*scale (+resid) ----------
// R8 discriminating experiment: 128x128 tile, BK=64, 256 thr (4 waves 2x2),
// per-wave 64x64 out, LDS 64KB -> TWO blocks/CU (cross-block overlap covers
// barrier/VM drains — the mechanism 256²/128KB forbids; R4/R6/R7 all neutral
// at 2 waves/SIMD single-block). Simple loop: 1 vmcnt(0) + 1 barrier per
// K-tile, full-tile prefetch after barrier, compiler schedules interior.
// Conflict-free XOR-swizzled LDS (T2, rule 21) + T1 swizzle + coalesced
// epilogues unchanged.
template<int OUTMODE>
__global__ __launch_bounds__(256, 2)
void gemm_bt_kernel(const u16* __restrict__ A, const u16* __restrict__ B,
                    void* __restrict__ C,
                    const float* __restrict__ bias,
                    const float* __restrict__ resid,
                    float scale, int K,
                    long long sA, long long sB, long long sC,
                    int ldc)
{
    // ---- XCD-bijective block swizzle (T1); all grids have nwg % 8 == 0.
    const unsigned nwg = gridDim.x * gridDim.y * gridDim.z;
    const unsigned bid = blockIdx.x + gridDim.x * (blockIdx.y + gridDim.y * blockIdx.z);
    const unsigned work = (bid & 7u) * (nwg >> 3) + (bid >> 3);
    const unsigned bx = work % gridDim.x;
    const unsigned rem = work / gridDim.x;
    const unsigned by = rem % gridDim.y;
    const unsigned bz = rem / gridDim.y;

    A += (long long)bz * sA;
    B += (long long)bz * sB;

    const int tid  = threadIdx.x;
    const int lane = tid & 63;
    const int w    = tid >> 6;    // 0..3
    const int wm   = w >> 1;      // 0..1
    const int wn   = w & 1;       // 0..1
    const int fr   = lane & 15;
    const int kg   = lane >> 4;
    const int swz  = (fr & 7) << 3;

    const int m0 = by * 128;
    const int n0 = bx * 128;

    __shared__ u16 lds[32768];    // 2 buffers x (A 128x64 + B 128x64) = 64KB

    f32x4 acc[4][4] = {};
    bf16x8 a0[4], a1[4], b0[4], b1[4];

    const int sr  = tid >> 3;              // 0..31
    const int sc8 = (tid & 7) << 3;        // u16 chunk col
    // inverse-swizzled global col depends on row (row & 7)
    const int nk = K >> 6;

#define STAGE(tt, bsel) { \
    const int kb_ = (tt) << 6; \
    u16* Ad_ = &lds[(bsel) * 16384]; \
    u16* Bd_ = Ad_ + 8192; \
    _Pragma("unroll") for (int j_ = 0; j_ < 4; ++j_) { \
        const int row_ = j_ * 32 + sr; \
        const int scb_ = sc8 ^ ((row_ & 7) << 3); \
        gload16(A + (size_t)(m0 + row_) * K + kb_ + scb_, &Ad_[row_ * 64 + sc8]); \
        gload16(B + (size_t)(n0 + row_) * K + kb_ + scb_, &Bd_[row_ * 64 + sc8]); \
    } }

#define READ_A(dst, ks) { const int cb_ = (((ks) << 5) | (kg << 3)) ^ swz; \
    _Pragma("unroll") for (int i_ = 0; i_ < 4; ++i_) \
      dst[i_] = *(const bf16x8*)&Alp[(wm * 64 + i_ * 16 + fr) * 64 + cb_]; }

#define READ_B(dst, ks) { const int cb_ = (((ks) << 5) | (kg << 3)) ^ swz; \
    _Pragma("unroll") for (int n_ = 0; n_ < 4; ++n_) \
      dst[n_] = *(const bf16x8*)&Blp[(wn * 64 + n_ * 16 + fr) * 64 + cb_]; }

#define MFMA_TILE(aset, bset) \
    _Pragma("unroll") for (int i_ = 0; i_ < 4; ++i_) \
      _Pragma("unroll") for (int n_ = 0; n_ < 4; ++n_) \
        acc[i_][n_] = __builtin_amdgcn_mfma_f32_16x16x32_bf16(aset[i_], bset[n_], acc[i_][n_], 0, 0, 0);

#define BAR()    __builtin_amdgcn_s_barrier()
#define SCHED0() __builtin_amdgcn_sched_barrier(0)
#define LGKM0()  { asm volatile("s_waitcnt lgkmcnt(0)" ::: "memory"); __builtin_amdgcn_sched_barrier(0); }
#define VM0()    asm volatile("s_waitcnt vmcnt(0)" ::: "memory")

    // prologue: stage tile 0 into buf 0
    STAGE(0, 0);

    for (int t = 0; t < nk; ++t) {
        VM0();          // tile t landed (issued one full tile ago, except t=0)
        BAR();          // visible to all; all waves done reading other buffer
        SCHED0();
        if (t + 1 < nk) { STAGE(t + 1, (t + 1) & 1); SCHED0(); }
        const u16* Alp = &lds[(t & 1) * 16384];
        const u16* Blp = Alp + 8192;
        READ_B(b0, 0); READ_A(a0, 0);
        MFMA_TILE(a0, b0);
        READ_B(b1, 1); READ_A(a1, 1);
        MFMA_TILE(a1, b1);
    }
    BAR();   // gates LDS reuse by epilogue

    // ---- coalesced epilogues via per-wave LDS transpose ----
    const int cc = lane & 15;
    const int rg = lane >> 4;

    if constexpr (OUTMODE == 0 || OUTMODE == 2) {
        float* ep = (float*)lds + w * 1088;   // [16][68] f32 per wave
        const int rcol = cc * 4;              // readback col 0..63
        float4 b4 = make_float4(0.f, 0.f, 0.f, 0.f);
        if (bias) b4 = *(const float4*)&bias[n0 + wn * 64 + rcol];
#pragma unroll
        for (int m = 0; m < 4; ++m) {
#pragma unroll
            for (int n = 0; n < 4; ++n)
#pragma unroll
                for (int r = 0; r < 4; ++r)
                    ep[(rg * 4 + r) * 68 + n * 16 + cc] = acc[m][n][r];
            LGKM0();
#pragma unroll
            for (int j = 0; j < 4; ++j) {
                const int row = j * 4 + rg;
                float4 v = *(const float4*)&ep[row * 68 + rcol];
                const int gr = m0 + wm * 64 + m * 16 + row;
                if constexpr (OUTMODE == 0) {
                    u16* Cb = (u16*)C + (long long)bz * sC;
                    ushort4 pk;
                    pk.x = f2b((v.x + b4.x) * scale);
                    pk.y = f2b((v.y + b4.y) * scale);
                    pk.z = f2b((v.z + b4.z) * scale);
                    pk.w = f2b((v.w + b4.w) * scale);
                    *(ushort4*)&Cb[(size_t)gr * ldc + n0 + wn * 64 + rcol] = pk;
                } else {
                    float* Cf = (float*)C;
                    size_t o = (size_t)gr * ldc + n0 + wn * 64 + rcol;
                    float4 rv = *(const float4*)&resid[o];
                    float4 ov;
                    ov.x = v.x + b4.x + rv.x;
                    ov.y = v.y + b4.y + rv.y;
                    ov.z = v.z + b4.z + rv.z;
                    ov.w = v.w + b4.w + rv.w;
                    *(float4*)&Cf[o] = ov;
                }
            }
            LGKM0();
        }
    } else {
        // OUTMODE 1: vT[b][hcol][s] — per-wave [64 cols][64 s] u16, XOR-swizzled
        u16* epW = &lds[w * 4096];
        const int colb = n0 + wn * 64;
        float bv4[4];
#pragma unroll
        for (int n = 0; n < 4; ++n) bv4[n] = bias ? bias[colb + n * 16 + cc] : 0.f;
#pragma unroll
        for (int n = 0; n < 4; ++n) {
            const int col = n * 16 + cc;
            const int swc = (col & 7) << 3;
#pragma unroll
            for (int m = 0; m < 4; ++m)
#pragma unroll
                for (int rp = 0; rp < 2; ++rp) {
                    const int s = m * 16 + rg * 4 + rp * 2;
                    unsigned lo = f2b((acc[m][n][rp * 2]     + bv4[n]) * scale);
                    unsigned hi = f2b((acc[m][n][rp * 2 + 1] + bv4[n]) * scale);
                    *(unsigned*)&epW[col * 64 + (s ^ swc)] = lo | (hi << 16);
                }
        }
        LGKM0();
        const int b  = (m0 + wm * 64) >> 11;
        const int sb = (m0 + wm * 64) & 2047;
        u16* Vb = (u16*)C;
#pragma unroll
        for (int j = 0; j < 8; ++j) {
            const int col = j * 8 + (lane >> 3);
            const int schunk = (lane & 7) * 8;
            const int sc_ = schunk ^ ((col & 7) << 3);
            bf16x8 v = *(const bf16x8*)&epW[col * 64 + sc_];
            *(bf16x8*)&Vb[((size_t)b * HID + colb + col) * SEQ + sb + schunk] = v;
        }
    }
#undef STAGE
#undef READ_A
#undef READ_B
#undef MFMA_TILE
#undef BAR
#undef SCHED0
#undef LGKM0
#undef VM0
}

// ---------- row softmax, in-place, bf16, row length 2048 ----------
__global__ __launch_bounds__(256)
void softmax_kernel(u16* __restrict__ sc) {
    const size_t row = blockIdx.x;
    u16* p = sc + row * 2048;
    const int tid = threadIdx.x;
    const int lane = tid & 63;
    const int w = tid >> 6;

    float v[8];
    ushort4 ua = *(const ushort4*)&p[tid * 8];
    ushort4 ub = *(const ushort4*)&p[tid * 8 + 4];
    v[0] = b2f(ua.x); v[1] = b2f(ua.y); v[2] = b2f(ua.z); v[3] = b2f(ua.w);
    v[4] = b2f(ub.x); v[5] = b2f(ub.y); v[6] = b2f(ub.z); v[7] = b2f(ub.w);

    float mx = v[0];
#pragma unroll
    for (int j = 1; j < 8; ++j) mx = fmaxf(mx, v[j]);
#pragma unroll
    for (int o = 32; o; o >>= 1) mx = fmaxf(mx, __shfl_xor(mx, o));

    __shared__ float red[8];
    if (!lane) red[w] = mx;
    __syncthreads();
    mx = fmaxf(fmaxf(red[0], red[1]), fmaxf(red[2], red[3]));

    float s = 0.f;
#pragma unroll
    for (int j = 0; j < 8; ++j) { v[j] = __expf(v[j] - mx); s += v[j]; }
#pragma unroll
    for (int o = 32; o; o >>= 1) s += __shfl_xor(s, o);
    if (!lane) red[4 + w] = s;
    __syncthreads();
    s = red[4] + red[5] + red[6] + red[7];
    float inv = 1.0f / s;

    ushort4 oa, ob;
    oa.x = f2b(v[0] * inv); oa.y = f2b(v[1] * inv); oa.z = f2b(v[2] * inv); oa.w = f2b(v[3] * inv);
    ob.x = f2b(v[4] * inv); ob.y = f2b(v[5] * inv); ob.z = f2b(v[6] * inv); ob.w = f2b(v[7] * inv);
    *(ushort4*)&p[tid * 8]     = oa;
    *(ushort4*)&p[tid * 8 + 4] = ob;
}

// ---------- in-place LayerNorm over rows of 1024 fp32 ----------
__global__ __launch_bounds__(256)
void layernorm_kernel(float* __restrict__ y,
                      const float* __restrict__ gamma,
                      const float* __restrict__ beta) {
    const size_t row = blockIdx.x;
    float* p = y + row * 1024;
    const int tid = threadIdx.x;
    const int lane = tid & 63;
    const int w = tid >> 6;

    float4 v = *(const float4*)&p[tid * 4];
    float s = v.x + v.y + v.z + v.w;
    float q = v.x * v.x + v.y * v.y + v.z * v.z + v.w * v.w;
#pragma unroll
    for (int o = 32; o; o >>= 1) { s += __shfl_xor(s, o); q += __shfl_xor(q, o); }

    __shared__ float red[16];
    if (!lane) { red[w] = s; red[8 + w] = q; }
    __syncthreads();
    s = red[0] + red[1] + red[2] + red[3];
    q = red[8] + red[9] + red[10] + red[11];

    const float mu  = s * (1.0f / 1024.0f);
    const float var = q * (1.0f / 1024.0f) - mu * mu;
    const float rs  = rsqrtf(var + 1e-5f);

    float4 g  = *(const float4*)&gamma[tid * 4];
    float4 be = *(const float4*)&beta[tid * 4];
    float4 o;
    o.x = (v.x - mu) * rs * g.x + be.x;
    o.y = (v.y - mu) * rs * g.y + be.y;
    o.z = (v.z - mu) * rs * g.z + be.z;
    o.w = (v.w - mu) * rs * g.w + be.w;
    *(float4*)&p[tid * 4] = o;
}

extern "C" void kernel_launch(void* const* d_in, const int* in_sizes, int n_in,
                              void* d_out, int out_size, void* d_ws, size_t ws_size,
                              hipStream_t stream) {
    const float* x     = (const float*)d_in[0];
    const float* Wq    = (const float*)d_in[1];
    const float* bq    = (const float*)d_in[2];
    const float* Wk    = (const float*)d_in[3];
    const float* bk    = (const float*)d_in[4];
    const float* Wv    = (const float*)d_in[5];
    const float* bv    = (const float*)d_in[6];
    const float* Wp    = (const float*)d_in[7];
    const float* bp    = (const float*)d_in[8];
    const float* gamma = (const float*)d_in[9];
    const float* beta  = (const float*)d_in[10];
    float* out = (float*)d_out;

    char* ws = (char*)d_ws;
    u16* xb     = (u16*)(ws + 0);
    u16* qb     = (u16*)(ws + 33554432);
    u16* kb     = (u16*)(ws + 67108864);
    u16* vT     = (u16*)(ws + 100663296);    // [8][1024][2048]
    u16* ctx    = (u16*)(ws + 134217728);
    u16* wqb    = (u16*)(ws + 167772160);
    u16* wkb    = (u16*)(ws + 169869312);
    u16* wvb    = (u16*)(ws + 171966464);
    u16* wpb    = (u16*)(ws + 174063616);
    u16* scores = (u16*)(ws + 176160768);

    cvt_kernel<<<16384, 256, 0, stream>>>(x,  xb,  NROWS * HID);
    cvt_kernel<<<1024, 256, 0, stream>>>(Wq, wqb, HID * HID);
    cvt_kernel<<<1024, 256, 0, stream>>>(Wk, wkb, HID * HID);
    cvt_kernel<<<1024, 256, 0, stream>>>(Wv, wvb, HID * HID);
    cvt_kernel<<<1024, 256, 0, stream>>>(Wp, wpb, HID * HID);

    dim3 blk(256);
    // q/k/v projections  (q folded with 1/sqrt(H)=1/32)
    gemm_bt_kernel<0><<<dim3(8, 128, 1), blk, 0, stream>>>(xb, wqb, qb, bq, nullptr, 0.03125f, HID, 0, 0, 0, HID);
    gemm_bt_kernel<0><<<dim3(8, 128, 1), blk, 0, stream>>>(xb, wkb, kb, bk, nullptr, 1.0f,     HID, 0, 0, 0, HID);
    gemm_bt_kernel<1><<<dim3(8, 128, 1), blk, 0, stream>>>(xb, wvb, vT, bv, nullptr, 1.0f,     HID, 0, 0, 0, 0);

    // scores = q' @ k^T  (per batch)
    gemm_bt_kernel<0><<<dim3(16, 16, 8), blk, 0, stream>>>(
        qb, kb, scores, nullptr, nullptr, 1.0f, HID,
        (long long)SEQ * HID, (long long)SEQ * HID, (long long)SEQ * SEQ, SEQ);

    softmax_kernel<<<NROWS, 256, 0, stream>>>(scores);

    // context = attn @ v  (B = vT, K-contiguous)
    gemm_bt_kernel<0><<<dim3(8, 16, 8), blk, 0, stream>>>(
        scores, vT, ctx, nullptr, nullptr, 1.0f, SEQ,
        (long long)SEQ * SEQ, (long long)HID * SEQ, (long long)SEQ * HID, HID);

    // out = ctx @ Wp^T + bp + x  (fp32 into d_out)
    gemm_bt_kernel<2><<<dim3(8, 128, 1), blk, 0, stream>>>(ctx, wpb, out, bp, x, 1.0f, HID, 0, 0, 0, HID);

    layernorm_kernel<<<NROWS, 256, 0, stream>>>(out, gamma, beta);
}

// Round 9
// 346.935 us; speedup vs baseline: 1.1639x; 1.1639x over previous
//
#include <hip/hip_runtime.h>
#include <hip/hip_bf16.h>

typedef __attribute__((ext_vector_type(4))) float f32x4;
typedef __attribute__((ext_vector_type(8))) short bf16x8;
typedef unsigned short u16;

#define SEQ 2048
#define HID 1024
#define NROWS 16384

// ---------- helpers ----------
__device__ __forceinline__ float b2f(u16 u) {
    union { float f; unsigned i; } x; x.i = ((unsigned)u) << 16; return x.f;
}
__device__ __forceinline__ u16 f2b(float f) {
    unsigned x = __float_as_uint(f);
    return (u16)((x + 0x7fffu + ((x >> 16) & 1u)) >> 16);
}
__device__ __forceinline__ void gload16(const u16* g, u16* l) {
    __builtin_amdgcn_global_load_lds(
        (const __attribute__((address_space(1))) void*)g,
        (__attribute__((address_space(3))) void*)l,
        16, 0, 0);
}

// ---------- fp32 -> bf16 convert ----------
__global__ __launch_bounds__(256)
void cvt_kernel(const float* __restrict__ src, u16* __restrict__ dst, int n) {
    int base = (blockIdx.x * 256 + threadIdx.x) * 4;
    if (base < n) {
        float4 v = *(const float4*)&src[base];
        ushort4 o;
        o.x = f2b(v.x); o.y = f2b(v.y); o.z = f2b(v.z); o.w = f2b(v.w);
        *(ushort4*)&dst[base] = o;
    }
}

// ---------- fp32 1024x1024 -> bf16 transposed ----------
__global__ __launch_bounds__(256)
void transpose_cvt_kernel(const float* __restrict__ src, u16* __restrict__ dst) {
    __shared__ u16 tile[64][66];
    const int j0 = blockIdx.y * 64;   // src row block
    const int i0 = blockIdx.x * 64;   // src col block
    const int tid = threadIdx.x;
#pragma unroll
    for (int k = 0; k < 16; ++k) {
        int idx = k * 256 + tid;
        int r = idx >> 6, c = idx & 63;
        tile[r][c] = f2b(src[(size_t)(j0 + r) * 1024 + i0 + c]);
    }
    __syncthreads();
#pragma unroll
    for (int k = 0; k < 16; ++k) {
        int idx = k * 256 + tid;
        int r = idx >> 6, c = idx & 63;
        dst[(size_t)(i0 + r) * 1024 + j0 + c] = tile[c][r];
    }
}

// ---------- bvp[o] = dot(Wp[o][:], bv)  (fp32) ----------
__global__ __launch_bounds__(64)
void bvp_kernel(const float* __restrict__ Wp, const float* __restrict__ bv,
                float* __restrict__ bvp) {
    const int lane = threadIdx.x;
    float bvv[16];
#pragma unroll
    for (int i = 0; i < 16; ++i) bvv[i] = bv[lane + i * 64];
#pragma unroll
    for (int q = 0; q < 4; ++q) {
        const int o = blockIdx.x * 4 + q;
        float s = 0.f;
#pragma unroll
        for (int i = 0; i < 16; ++i) s += Wp[(size_t)o * 1024 + lane + i * 64] * bvv[i];
#pragma unroll
        for (int off = 32; off; off >>= 1) s += __shfl_xor(s, off);
        if (!lane) bvp[o] = s;
    }
}

// ---------- GEMM: C = A @ B^T (+bias)*scale (+resid) ----------
// 256x256 tile, BK=64, 512 thr (8 waves 2Mx4N), 16x16x32 MFMA,
// conflict-free XOR-swizzled LDS, 1 barrier + 1 vmcnt(0) per K-tile (R7).
// OUTMODE 0: bf16 write (ldc), batch bz*sC (elem offset)
// OUTMODE 1: bf16 transposed write to vT[b][col][s], bias fp32 ptr
// OUTMODE 2: fp32 write + bias + resid; row offset bz*sC (sC = rows/batch)
template<int OUTMODE>
__global__ __launch_bounds__(512, 2)
void gemm_bt_kernel(const u16* __restrict__ A, const u16* __restrict__ B,
                    void* __restrict__ C,
                    const float* __restrict__ bias,
                    const float* __restrict__ resid,
                    float scale, int K,
                    long long sA, long long sB, long long sC,
                    int ldc)
{
    const unsigned nwg = gridDim.x * gridDim.y * gridDim.z;
    const unsigned bid = blockIdx.x + gridDim.x * (blockIdx.y + gridDim.y * blockIdx.z);
    const unsigned work = (bid & 7u) * (nwg >> 3) + (bid >> 3);
    const unsigned bx = work % gridDim.x;
    const unsigned rem = work / gridDim.x;
    const unsigned by = rem % gridDim.y;
    const unsigned bz = rem / gridDim.y;

    A += (long long)bz * sA;
    B += (long long)bz * sB;

    const int tid  = threadIdx.x;
    const int lane = tid & 63;
    const int w    = tid >> 6;
    const int wm   = w >> 2;
    const int wn   = w & 3;
    const int fr   = lane & 15;
    const int kg   = lane >> 4;
    const int swz  = (fr & 7) << 3;

    const int m0 = by * 256;
    const int n0 = bx * 256;

    __shared__ u16 lds[65536];

    f32x4 acc[8][4] = {};
    bf16x8 a00[4], a10[4], a01[4], a11[4], b0[4], b1[4];

    const int sr  = tid >> 3;
    const int sc8 = (tid & 7) << 3;
    const int scb = sc8 ^ ((sr & 7) << 3);

    const int nk = K >> 6;

#define STAGE_A(tt, q01, bsel) { \
    const int kb_ = (tt) << 6; \
    u16* dst_ = &lds[(bsel) * 32768]; \
    { const int row_ = (q01) * 64 + sr; \
      gload16(A + (size_t)(m0 + row_) * K + kb_ + scb, &dst_[row_ * 64 + sc8]); } \
    { const int row_ = ((q01) + 2) * 64 + sr; \
      gload16(A + (size_t)(m0 + row_) * K + kb_ + scb, &dst_[row_ * 64 + sc8]); } }

#define STAGE_B(tt, h, bsel) { \
    const int kb_ = (tt) << 6; \
    u16* dst_ = &lds[(bsel) * 32768 + 16384]; \
    { const int row_ = (h) * 128 + sr; \
      gload16(B + (size_t)(n0 + row_) * K + kb_ + scb, &dst_[row_ * 64 + sc8]); } \
    { const int row_ = (h) * 128 + 64 + sr; \
      gload16(B + (size_t)(n0 + row_) * K + kb_ + scb, &dst_[row_ * 64 + sc8]); } }

#define READ_A(dst, mh, ks) { const int cb_ = (((ks) << 5) | (kg << 3)) ^ swz; \
    _Pragma("unroll") for (int i_ = 0; i_ < 4; ++i_) \
      dst[i_] = *(const bf16x8*)&Alp[(wm * 128 + (mh) * 64 + i_ * 16 + fr) * 64 + cb_]; }

#define READ_B(dst, ks) { const int cb_ = (((ks) << 5) | (kg << 3)) ^ swz; \
    _Pragma("unroll") for (int n_ = 0; n_ < 4; ++n_) \
      dst[n_] = *(const bf16x8*)&Blp[(wn * 64 + n_ * 16 + fr) * 64 + cb_]; }

#define MFMA_PH(mh, aset, bset) \
    _Pragma("unroll") for (int i_ = 0; i_ < 4; ++i_) \
      _Pragma("unroll") for (int n_ = 0; n_ < 4; ++n_) \
        acc[(mh)*4 + i_][n_] = __builtin_amdgcn_mfma_f32_16x16x32_bf16(aset[i_], bset[n_], acc[(mh)*4 + i_][n_], 0, 0, 0);

#define BAR()    __builtin_amdgcn_s_barrier()
#define SCHED0() __builtin_amdgcn_sched_barrier(0)
#define LGKM0()  { asm volatile("s_waitcnt lgkmcnt(0)" ::: "memory"); __builtin_amdgcn_sched_barrier(0); }
#define VM0()    asm volatile("s_waitcnt vmcnt(0)" ::: "memory")

    STAGE_A(0, 0, 0); STAGE_B(0, 0, 0); STAGE_B(0, 1, 0); STAGE_A(0, 1, 0);

    for (int t = 0; t < nk; ++t) {
        VM0();
        BAR();
        SCHED0();
        if (t + 1 < nk) {
            const int nb = (t + 1) & 1;
            STAGE_A(t + 1, 0, nb); STAGE_B(t + 1, 0, nb);
            STAGE_B(t + 1, 1, nb); STAGE_A(t + 1, 1, nb);
            SCHED0();
        }
        const u16* Alp = &lds[(t & 1) * 32768];
        const u16* Blp = Alp + 16384;
        READ_B(b0, 0); READ_A(a00, 0, 0);
        MFMA_PH(0, a00, b0);
        READ_A(a10, 1, 0);
        MFMA_PH(1, a10, b0);
        READ_B(b1, 1); READ_A(a01, 0, 1);
        MFMA_PH(0, a01, b1);
        READ_A(a11, 1, 1);
        MFMA_PH(1, a11, b1);
    }
    BAR();

    const int cc = lane & 15;
    const int rg = lane >> 4;

    if constexpr (OUTMODE == 0 || OUTMODE == 2) {
        float* ep = (float*)lds + w * 1088;
        const int rcol = cc * 4;
        float4 b4 = make_float4(0.f, 0.f, 0.f, 0.f);
        if (bias) b4 = *(const float4*)&bias[n0 + wn * 64 + rcol];
#pragma unroll
        for (int m = 0; m < 8; ++m) {
#pragma unroll
            for (int n = 0; n < 4; ++n)
#pragma unroll
                for (int r = 0; r < 4; ++r)
                    ep[(rg * 4 + r) * 68 + n * 16 + cc] = acc[m][n][r];
            LGKM0();
#pragma unroll
            for (int j = 0; j < 4; ++j) {
                const int row = j * 4 + rg;
                float4 v = *(const float4*)&ep[row * 68 + rcol];
                const int gr = m0 + wm * 128 + m * 16 + row;
                if constexpr (OUTMODE == 0) {
                    u16* Cb = (u16*)C + (long long)bz * sC;
                    ushort4 pk;
                    pk.x = f2b((v.x + b4.x) * scale);
                    pk.y = f2b((v.y + b4.y) * scale);
                    pk.z = f2b((v.z + b4.z) * scale);
                    pk.w = f2b((v.w + b4.w) * scale);
                    *(ushort4*)&Cb[(size_t)gr * ldc + n0 + wn * 64 + rcol] = pk;
                } else {
                    float* Cf = (float*)C;
                    size_t o = ((size_t)bz * sC + gr) * ldc + n0 + wn * 64 + rcol;
                    float4 rv = *(const float4*)&resid[o];
                    float4 ov;
                    ov.x = v.x + b4.x + rv.x;
                    ov.y = v.y + b4.y + rv.y;
                    ov.z = v.z + b4.z + rv.z;
                    ov.w = v.w + b4.w + rv.w;
                    *(float4*)&Cf[o] = ov;
                }
            }
            LGKM0();
        }
    } else {
        // OUTMODE 1: vT[b][hcol][s] — full-LDS bf16 transpose, XOR-swizzled
        u16* epW = &lds[w * 8192];
        const int colb = n0 + wn * 64;
        float bv4[4];
#pragma unroll
        for (int n = 0; n < 4; ++n) bv4[n] = bias ? bias[colb + n * 16 + cc] : 0.f;
        const int swc = (cc & 7) << 3;
#pragma unroll
        for (int n = 0; n < 4; ++n) {
            const int col = n * 16 + cc;
#pragma unroll
            for (int m = 0; m < 8; ++m)
#pragma unroll
                for (int rp = 0; rp < 2; ++rp) {
                    const int s = m * 16 + rg * 4 + rp * 2;
                    unsigned lo = f2b((acc[m][n][rp * 2]     + bv4[n]) * scale);
                    unsigned hi = f2b((acc[m][n][rp * 2 + 1] + bv4[n]) * scale);
                    *(unsigned*)&epW[col * 128 + (s ^ swc)] = lo | (hi << 16);
                }
        }
        LGKM0();
        const int b  = (m0 + wm * 128) >> 11;
        const int sb = (m0 + wm * 128) & 2047;
        u16* Vb = (u16*)C;
#pragma unroll
        for (int j = 0; j < 16; ++j) {
            const int col = j * 4 + rg;
            const int sc_ = (cc * 8) ^ ((col & 7) << 3);
            bf16x8 v = *(const bf16x8*)&epW[col * 128 + sc_];
            *(bf16x8*)&Vb[((size_t)b * HID + colb + col) * SEQ + sb + cc * 8] = v;
        }
    }
#undef STAGE_A
#undef STAGE_B
#undef READ_A
#undef READ_B
#undef MFMA_PH
#undef BAR
#undef SCHED0
#undef LGKM0
#undef VM0
}

// ---------- small GEMM (128x128 tile, R8-proven) for Wvp = Wp @ Wv ----------
// C[o][i] bf16 = sum_j A[o][j] * B[i][j]; grid must have nwg%8==0.
__global__ __launch_bounds__(256, 2)
void gemm128_kernel(const u16* __restrict__ A, const u16* __restrict__ B,
                    u16* __restrict__ C, int K, int ldc)
{
    const unsigned nwg = gridDim.x * gridDim.y;
    const unsigned bid = blockIdx.x + gridDim.x * blockIdx.y;
    const unsigned work = (bid & 7u) * (nwg >> 3) + (bid >> 3);
    const unsigned bx = work % gridDim.x;
    const unsigned by = work / gridDim.x;

    const int tid  = threadIdx.x;
    const int lane = tid & 63;
    const int w    = tid >> 6;
    const int wm   = w >> 1;
    const int wn   = w & 1;
    const int fr   = lane & 15;
    const int kg   = lane >> 4;
    const int swz  = (fr & 7) << 3;

    const int m0 = by * 128;
    const int n0 = bx * 128;

    __shared__ u16 lds[32768];

    f32x4 acc[4][4] = {};
    bf16x8 a0[4], a1[4], b0[4], b1[4];

    const int sr  = tid >> 3;
    const int sc8 = (tid & 7) << 3;
    const int nk = K >> 6;

#define STAGE(tt, bsel) { \
    const int kb_ = (tt) << 6; \
    u16* Ad_ = &lds[(bsel) * 16384]; \
    u16* Bd_ = Ad_ + 8192; \
    _Pragma("unroll") for (int j_ = 0; j_ < 4; ++j_) { \
        const int row_ = j_ * 32 + sr; \
        const int scb_ = sc8 ^ ((row_ & 7) << 3); \
        gload16(A + (size_t)(m0 + row_) * K + kb_ + scb_, &Ad_[row_ * 64 + sc8]); \
        gload16(B + (size_t)(n0 + row_) * K + kb_ + scb_, &Bd_[row_ * 64 + sc8]); \
    } }

#define READ_A(dst, ks) { const int cb_ = (((ks) << 5) | (kg << 3)) ^ swz; \
    _Pragma("unroll") for (int i_ = 0; i_ < 4; ++i_) \
      dst[i_] = *(const bf16x8*)&Alp[(wm * 64 + i_ * 16 + fr) * 64 + cb_]; }

#define READ_B(dst, ks) { const int cb_ = (((ks) << 5) | (kg << 3)) ^ swz; \
    _Pragma("unroll") for (int n_ = 0; n_ < 4; ++n_) \
      dst[n_] = *(const bf16x8*)&Blp[(wn * 64 + n_ * 16 + fr) * 64 + cb_]; }

#define MFMA_TILE(aset, bset) \
    _Pragma("unroll") for (int i_ = 0; i_ < 4; ++i_) \
      _Pragma("unroll") for (int n_ = 0; n_ < 4; ++n_) \
        acc[i_][n_] = __builtin_amdgcn_mfma_f32_16x16x32_bf16(aset[i_], bset[n_], acc[i_][n_], 0, 0, 0);

    STAGE(0, 0);
    for (int t = 0; t < nk; ++t) {
        asm volatile("s_waitcnt vmcnt(0)" ::: "memory");
        __builtin_amdgcn_s_barrier();
        __builtin_amdgcn_sched_barrier(0);
        if (t + 1 < nk) { STAGE(t + 1, (t + 1) & 1); __builtin_amdgcn_sched_barrier(0); }
        const u16* Alp = &lds[(t & 1) * 16384];
        const u16* Blp = Alp + 8192;
        READ_B(b0, 0); READ_A(a0, 0);
        MFMA_TILE(a0, b0);
        READ_B(b1, 1); READ_A(a1, 1);
        MFMA_TILE(a1, b1);
    }
    __builtin_amdgcn_s_barrier();

    const int cc = lane & 15;
    const int rg = lane >> 4;
    float* ep = (float*)lds + w * 1088;
    const int rcol = cc * 4;
#pragma unroll
    for (int m = 0; m < 4; ++m) {
#pragma unroll
        for (int n = 0; n < 4; ++n)
#pragma unroll
            for (int r = 0; r < 4; ++r)
                ep[(rg * 4 + r) * 68 + n * 16 + cc] = acc[m][n][r];
        asm volatile("s_waitcnt lgkmcnt(0)" ::: "memory");
        __builtin_amdgcn_sched_barrier(0);
#pragma unroll
        for (int j = 0; j < 4; ++j) {
            const int row = j * 4 + rg;
            float4 v = *(const float4*)&ep[row * 68 + rcol];
            const int gr = m0 + wm * 64 + m * 16 + row;
            ushort4 pk;
            pk.x = f2b(v.x); pk.y = f2b(v.y); pk.z = f2b(v.z); pk.w = f2b(v.w);
            *(ushort4*)&C[(size_t)gr * ldc + n0 + wn * 64 + rcol] = pk;
        }
        asm volatile("s_waitcnt lgkmcnt(0)" ::: "memory");
        __builtin_amdgcn_sched_barrier(0);
    }
#undef STAGE
#undef READ_A
#undef READ_B
#undef MFMA_TILE
}

// ---------- row softmax, in-place, bf16, row length 2048 ----------
__global__ __launch_bounds__(256)
void softmax_kernel(u16* __restrict__ sc) {
    const size_t row = blockIdx.x;
    u16* p = sc + row * 2048;
    const int tid = threadIdx.x;
    const int lane = tid & 63;
    const int w = tid >> 6;

    float v[8];
    ushort4 ua = *(const ushort4*)&p[tid * 8];
    ushort4 ub = *(const ushort4*)&p[tid * 8 + 4];
    v[0] = b2f(ua.x); v[1] = b2f(ua.y); v[2] = b2f(ua.z); v[3] = b2f(ua.w);
    v[4] = b2f(ub.x); v[5] = b2f(ub.y); v[6] = b2f(ub.z); v[7] = b2f(ub.w);

    float mx = v[0];
#pragma unroll
    for (int j = 1; j < 8; ++j) mx = fmaxf(mx, v[j]);
#pragma unroll
    for (int o = 32; o; o >>= 1) mx = fmaxf(mx, __shfl_xor(mx, o));

    __shared__ float red[8];
    if (!lane) red[w] = mx;
    __syncthreads();
    mx = fmaxf(fmaxf(red[0], red[1]), fmaxf(red[2], red[3]));

    float s = 0.f;
#pragma unroll
    for (int j = 0; j < 8; ++j) { v[j] = __expf(v[j] - mx); s += v[j]; }
#pragma unroll
    for (int o = 32; o; o >>= 1) s += __shfl_xor(s, o);
    if (!lane) red[4 + w] = s;
    __syncthreads();
    s = red[4] + red[5] + red[6] + red[7];
    float inv = 1.0f / s;

    ushort4 oa, ob;
    oa.x = f2b(v[0] * inv); oa.y = f2b(v[1] * inv); oa.z = f2b(v[2] * inv); oa.w = f2b(v[3] * inv);
    ob.x = f2b(v[4] * inv); ob.y = f2b(v[5] * inv); ob.z = f2b(v[6] * inv); ob.w = f2b(v[7] * inv);
    *(ushort4*)&p[tid * 8]     = oa;
    *(ushort4*)&p[tid * 8 + 4] = ob;
}

// ---------- in-place LayerNorm over rows of 1024 fp32 ----------
__global__ __launch_bounds__(256)
void layernorm_kernel(float* __restrict__ y,
                      const float* __restrict__ gamma,
                      const float* __restrict__ beta) {
    const size_t row = blockIdx.x;
    float* p = y + row * 1024;
    const int tid = threadIdx.x;
    const int lane = tid & 63;
    const int w = tid >> 6;

    float4 v = *(const float4*)&p[tid * 4];
    float s = v.x + v.y + v.z + v.w;
    float q = v.x * v.x + v.y * v.y + v.z * v.z + v.w * v.w;
#pragma unroll
    for (int o = 32; o; o >>= 1) { s += __shfl_xor(s, o); q += __shfl_xor(q, o); }

    __shared__ float red[16];
    if (!lane) { red[w] = s; red[8 + w] = q; }
    __syncthreads();
    s = red[0] + red[1] + red[2] + red[3];
    q = red[8] + red[9] + red[10] + red[11];

    const float mu  = s * (1.0f / 1024.0f);
    const float var = q * (1.0f / 1024.0f) - mu * mu;
    const float rs  = rsqrtf(var + 1e-5f);

    float4 g  = *(const float4*)&gamma[tid * 4];
    float4 be = *(const float4*)&beta[tid * 4];
    float4 o;
    o.x = (v.x - mu) * rs * g.x + be.x;
    o.y = (v.y - mu) * rs * g.y + be.y;
    o.z = (v.z - mu) * rs * g.z + be.z;
    o.w = (v.w - mu) * rs * g.w + be.w;
    *(float4*)&p[tid * 4] = o;
}

extern "C" void kernel_launch(void* const* d_in, const int* in_sizes, int n_in,
                              void* d_out, int out_size, void* d_ws, size_t ws_size,
                              hipStream_t stream) {
    const float* x     = (const float*)d_in[0];
    const float* Wq    = (const float*)d_in[1];
    const float* bq    = (const float*)d_in[2];
    const float* Wk    = (const float*)d_in[3];
    const float* bk    = (const float*)d_in[4];
    const float* Wv    = (const float*)d_in[5];
    const float* bv    = (const float*)d_in[6];
    const float* Wp    = (const float*)d_in[7];
    const float* bp    = (const float*)d_in[8];
    const float* gamma = (const float*)d_in[9];
    const float* beta  = (const float*)d_in[10];
    float* out = (float*)d_out;

    char* ws = (char*)d_ws;
    u16*   xb     = (u16*)(ws + 0);            // 32 MB
    u16*   qb     = (u16*)(ws + 33554432);     // 32 MB
    u16*   kb     = (u16*)(ws + 67108864);     // 32 MB
    u16*   vT     = (u16*)(ws + 100663296);    // 32 MB [8][1024][2048]
    u16*   wqb    = (u16*)(ws + 134217728);    // 2 MB
    u16*   wkb    = (u16*)(ws + 136314880);    // 2 MB
    u16*   wpb    = (u16*)(ws + 138412032);    // 2 MB (unused by GEMM; kept for clarity)
    u16*   wvT    = (u16*)(ws + 140509184);    // 2 MB (Wv^T bf16)
    u16*   wvpb   = (u16*)(ws + 142606336);    // 2 MB (Wp@Wv bf16)
    float* bvp    = (float*)(ws + 144703488);  // 4 KB
    u16*   scores = (u16*)(ws + 144769024);    // 64 MB

    // ---- precompute: Wvp = Wp @ Wv, bvp = Wp @ bv ----
    cvt_kernel<<<1024, 256, 0, stream>>>(Wp, wpb, HID * HID);
    transpose_cvt_kernel<<<dim3(16, 16), 256, 0, stream>>>(Wv, wvT);
    bvp_kernel<<<256, 64, 0, stream>>>(Wp, bv, bvp);
    gemm128_kernel<<<dim3(8, 8), 256, 0, stream>>>(wpb, wvT, wvpb, HID, HID);

    // ---- converts ----
    cvt_kernel<<<16384, 256, 0, stream>>>(x,  xb,  NROWS * HID);
    cvt_kernel<<<1024, 256, 0, stream>>>(Wq, wqb, HID * HID);
    cvt_kernel<<<1024, 256, 0, stream>>>(Wk, wkb, HID * HID);

    dim3 blk(512);
    // q/k projections (q epilogue folds 1/sqrt(H)=1/32)
    gemm_bt_kernel<0><<<dim3(4, 64, 1), blk, 0, stream>>>(xb, wqb, qb, bq, nullptr, 0.03125f, HID, 0, 0, 0, HID);
    gemm_bt_kernel<0><<<dim3(4, 64, 1), blk, 0, stream>>>(xb, wkb, kb, bk, nullptr, 1.0f,     HID, 0, 0, 0, HID);
    // vp-projection: vp = x @ Wvp^T + bvp, stored transposed vT[b][h][s]
    gemm_bt_kernel<1><<<dim3(4, 64, 1), blk, 0, stream>>>(xb, wvpb, vT, bvp, nullptr, 1.0f, HID, 0, 0, 0, 0);

    // scores = q' @ k^T  (per batch)
    gemm_bt_kernel<0><<<dim3(8, 8, 8), blk, 0, stream>>>(
        qb, kb, scores, nullptr, nullptr, 1.0f, HID,
        (long long)SEQ * HID, (long long)SEQ * HID, (long long)SEQ * SEQ, SEQ);

    softmax_kernel<<<NROWS, 256, 0, stream>>>(scores);

    // out = attn @ vp + bp + x   (fp32 into d_out; batched rows bz*2048)
    gemm_bt_kernel<2><<<dim3(4, 8, 8), blk, 0, stream>>>(
        scores, vT, out, bp, x, 1.0f, SEQ,
        (long long)SEQ * SEQ, (long long)HID * SEQ, (long long)SEQ, HID);

    layernorm_kernel<<<NROWS, 256, 0, stream>>>(out, gamma, beta);
}